// Round 11
// baseline (445.710 us; speedup 1.0000x reference)
//
#include <hip/hip_runtime.h>
#include <math.h>

// Problem constants (from reference)
#define B_   8
#define S_   2048
#define DIN_ 4096
#define DOUT_ 4096
#define THRESH_ 0.1f
#define LN_EPS_ 1e-5f

#define NROWS (B_ * S_)
#define RPB 8                      // rows per block in the row kernel

// ---------------------------------------------------------------------------
// Fast tanh-quantize: out = rint(127*tanh(z*iq))/127 via v_exp_f32+v_rcp_f32.
// Max tanh error ~1e-6 -> only matters exactly at a bin boundary -> <= 1/127
// output delta, far below the 2e-2 threshold. (Measured absmax 0.0, r6/r9.)
// ---------------------------------------------------------------------------
__device__ __forceinline__ float qtanh(float z, float iq) {
  float t = z * iq;
  t = fminf(fmaxf(t, -9.f), 9.f);
  float e2 = __expf(2.f * t);
  float r = (e2 - 1.f) * __builtin_amdgcn_rcpf(e2 + 1.f);
  return rintf(r * 127.f) * (1.f / 127.f);
}

// ---------------------------------------------------------------------------
// Kernel 1: scan weight [DOUT, DIN] for ternary nonzeros (|w| >= THRESH).
// nnz ~ Poisson(2) for this init (weight=(u-0.5)*0.2 in [-0.1,0.1); only
// exact u==0 survives -> w=-0.1f). General for any nnz up to ws capacity.
// ---------------------------------------------------------------------------
__global__ __launch_bounds__(256) void lbe_scan_kernel(
    const float* __restrict__ w, int* __restrict__ cnt,
    int* __restrict__ list, int cap) {
  int idx = blockIdx.x * blockDim.x + threadIdx.x;  // float4 index
  const int total4 = (DOUT_ * DIN_) / 4;
  if (idx >= total4) return;
  float4 v = reinterpret_cast<const float4*>(w)[idx];
  const float* vp = &v.x;
#pragma unroll
  for (int j = 0; j < 4; ++j) {
    float wv = vp[j];
    if (fabsf(wv) >= THRESH_) {
      int flat = idx * 4 + j;                       // o*DIN + i, < 2^24
      int e = (flat << 1) | (wv < 0.f ? 1 : 0);
      int pos = atomicAdd(cnt, 1);
      if (pos < cap) list[pos] = e;
    }
  }
}

// ---------------------------------------------------------------------------
// Kernel 2 (1 block): S0 = sum(bias*scale), Q0 = sum((bias*scale)^2).
// Input-independent parts of the LN mean / second moment: y_o=(dot_o+b_o)*s_o
// and dot_o == 0 for all non-hit channels.
// ---------------------------------------------------------------------------
__global__ __launch_bounds__(256) void lbe_base_kernel(
    const float* __restrict__ bias, const float* __restrict__ scale,
    float* __restrict__ sq) {
  int tid = threadIdx.x;
  float s = 0.f, q = 0.f;
#pragma unroll
  for (int k = 0; k < 4; ++k) {
    float4 b  = reinterpret_cast<const float4*>(bias)[tid + k * 256];
    float4 sc = reinterpret_cast<const float4*>(scale)[tid + k * 256];
    float p;
    p = b.x * sc.x; s += p; q = fmaf(p, p, q);
    p = b.y * sc.y; s += p; q = fmaf(p, p, q);
    p = b.z * sc.z; s += p; q = fmaf(p, p, q);
    p = b.w * sc.w; s += p; q = fmaf(p, p, q);
  }
#pragma unroll
  for (int off = 32; off > 0; off >>= 1) {
    s += __shfl_xor(s, off);
    q += __shfl_xor(q, off);
  }
  __shared__ float red[8];
  int wid = tid >> 6, lane = tid & 63;
  if (lane == 0) { red[wid] = s; red[4 + wid] = q; }
  __syncthreads();
  if (tid == 0) {
    sq[0] = red[0] + red[1] + red[2] + red[3];
    sq[1] = red[4] + red[5] + red[6] + red[7];
  }
}

// ---------------------------------------------------------------------------
// Kernel 3: streaming epilogue, stats fused. 256 threads x RPB rows/block;
// each thread owns 16 channels (4 float4 groups, o4 = tid + k*256). No LDS,
// no syncs, no reductions, no murs round-trip: the per-row LN corrections
// dS/dQ involve only the nnz hit channels, so EVERY thread computes them
// redundantly in registers (uniform-address loads -> cache broadcast;
// O(n^2) dedupe with n~2 is a dozen VALU ops).
// ---------------------------------------------------------------------------
__global__ __launch_bounds__(256) void lbe_row_kernel(
    const float* __restrict__ x, const float* __restrict__ bias,
    const float* __restrict__ scale, const float* __restrict__ gamma,
    const float* __restrict__ beta, const float* __restrict__ qs,
    const int* __restrict__ cnt, const int* __restrict__ list, int cap,
    const float* __restrict__ sq, float* __restrict__ out) {
  const int tid = threadIdx.x;
  float4 b4[4], s4[4], g4[4], e4[4];
#pragma unroll
  for (int k = 0; k < 4; ++k) {
    int o4 = tid + k * 256;
    b4[k] = reinterpret_cast<const float4*>(bias)[o4];
    s4[k] = reinterpret_cast<const float4*>(scale)[o4];
    g4[k] = reinterpret_cast<const float4*>(gamma)[o4];
    e4[k] = reinterpret_cast<const float4*>(beta)[o4];
  }
  int n = *cnt; if (n > cap) n = cap;
  const float iq = __builtin_amdgcn_rcpf(qs[0]);   // qs=10 -> ~1ulp, feeds tanh arg
  const float S0 = sq[0], Q0 = sq[1];

  const int row0 = blockIdx.x * RPB;
  for (int r = 0; r < RPB; ++r) {
    const int row = row0 + r;
    const float* __restrict__ xr = x + (size_t)row * DIN_;

    // --- per-thread-owned sparse dot accumulation + redundant LN stats ---
    float4 d[4];
#pragma unroll
    for (int k = 0; k < 4; ++k) d[k] = make_float4(0.f, 0.f, 0.f, 0.f);
    float dS = 0.f, dQ = 0.f;
    for (int e = 0; e < n; ++e) {
      int ev = list[e];
      int o = ev >> 13;                            // channel index
      float c = xr[(ev >> 1) & (DIN_ - 1)];        // broadcast load
      if (ev & 1) c = -c;
      // own-channel accumulation (compile-time-indexed predicated adds)
#pragma unroll
      for (int k = 0; k < 4; ++k) {
        int base = (tid + k * 256) << 2;
        d[k].x += (o == base + 0) ? c : 0.f;
        d[k].y += (o == base + 1) ? c : 0.f;
        d[k].z += (o == base + 2) ? c : 0.f;
        d[k].w += (o == base + 3) ? c : 0.f;
      }
      // stats correction: process each unique o once (dedupe vs earlier e)
      bool first = true;
      for (int e2 = 0; e2 < e; ++e2)
        if ((list[e2] >> 13) == o) { first = false; break; }
      if (!first) continue;
      float dotO = c;
      for (int e2 = e + 1; e2 < n; ++e2) {
        int ev2 = list[e2];
        if ((ev2 >> 13) == o) {
          float c2 = xr[(ev2 >> 1) & (DIN_ - 1)];
          dotO += (ev2 & 1) ? -c2 : c2;
        }
      }
      float bo = bias[o], so = scale[o];
      float t1 = (dotO + bo) * so;
      float t0 = bo * so;
      dS += dotO * so;
      dQ += t1 * t1 - t0 * t0;
    }
    float S = S0 + dS, Q = Q0 + dQ;
    float mu = S * (1.f / DOUT_);
    float var = Q * (1.f / DOUT_) - mu * mu;
    if (var < 0.f) var = 0.f;
    const float rs = rsqrtf(var + LN_EPS_);

    // --- normalize + quantize + stream out ---
    float* __restrict__ orow = out + (size_t)row * DOUT_;
#pragma unroll
    for (int k = 0; k < 4; ++k) {
      float4 y, rr;
      y.x = (d[k].x + b4[k].x) * s4[k].x;
      y.y = (d[k].y + b4[k].y) * s4[k].y;
      y.z = (d[k].z + b4[k].z) * s4[k].z;
      y.w = (d[k].w + b4[k].w) * s4[k].w;
      rr.x = qtanh(fmaf((y.x - mu) * rs, g4[k].x, e4[k].x), iq);
      rr.y = qtanh(fmaf((y.y - mu) * rs, g4[k].y, e4[k].y), iq);
      rr.z = qtanh(fmaf((y.z - mu) * rs, g4[k].z, e4[k].z), iq);
      rr.w = qtanh(fmaf((y.w - mu) * rs, g4[k].w, e4[k].w), iq);
      reinterpret_cast<float4*>(orow)[tid + k * 256] = rr;
    }
  }
}

extern "C" void kernel_launch(void* const* d_in, const int* in_sizes, int n_in,
                              void* d_out, int out_size, void* d_ws, size_t ws_size,
                              hipStream_t stream) {
  const float* x     = (const float*)d_in[0];  // [B,S,DIN]
  const float* w     = (const float*)d_in[1];  // [DOUT,DIN]
  const float* bias  = (const float*)d_in[2];  // [DOUT]
  const float* scale = (const float*)d_in[3];  // [DOUT]
  const float* gamma = (const float*)d_in[4];  // [DOUT]
  const float* beta  = (const float*)d_in[5];  // [DOUT]
  const float* qs    = (const float*)d_in[6];  // [1]
  float* out = (float*)d_out;

  // ws layout: [0..4) cnt | [16..24) S0,Q0 | [256 ..) list
  int*   cnt = (int*)d_ws;
  float* sq  = (float*)((char*)d_ws + 16);
  int*  list = (int*)((char*)d_ws + 256);
  long long avail = (long long)ws_size - 256;
  int cap = avail > 0 ? (int)(avail / 4) : 0;
  if (cap > (1 << 24)) cap = 1 << 24;

  hipMemsetAsync(d_ws, 0, 4, stream);   // zero nnz counter

  {
    const int total4 = (DOUT_ * DIN_) / 4;
    lbe_scan_kernel<<<(total4 + 255) / 256, 256, 0, stream>>>(w, cnt, list, cap);
  }
  lbe_base_kernel<<<1, 256, 0, stream>>>(bias, scale, sq);
  lbe_row_kernel<<<NROWS / RPB, 256, 0, stream>>>(x, bias, scale, gamma, beta,
                                                  qs, cnt, list, cap, sq, out);
}